// Round 15
// baseline (204.322 us; speedup 1.0000x reference)
//
#include <hip/hip_runtime.h>
#include <stdint.h>

// VectorQuantization: 2 kernels. prep (pack bf16 B frags + sq_e) + fused
// (MFMA distances, argmin, gather, loss, and last-block tail: histogram +
// perplexity). Only ONE global atomic per block (block-done counter).
// N=65536 rows, D=64, K=512 codebook (uniform ±1/512 -> argmin flips bounded
// at 0.0039 in output-0; perplexity shift << 2% tol).
// dist = (|e|^2 + xh.eh[0:32]) + (xh.eh[32:64]) via two INDEPENDENT MFMAs
// (R15-A: breaks the serial MFMA chain; 1-ulp vs R11, safe per bound above).
// R15-B: hist+final fused as a tail in the last-finishing block.

#define VQ_N 65536
#define VQ_D 64
#define VQ_K 512
#define NBLK 512

typedef __attribute__((ext_vector_type(4))) float f32x4;
typedef __attribute__((ext_vector_type(8))) short bf16x8;

__device__ __forceinline__ unsigned short f2bf(float f) {  // RNE
    unsigned b = __float_as_uint(f);
    return (unsigned short)((b + 0x7fffu + ((b >> 16) & 1u)) >> 16);
}

__device__ __forceinline__ void gld_lds16(const void* g, void* l) {
    __builtin_amdgcn_global_load_lds(
        (const __attribute__((address_space(1))) void*)g,
        (__attribute__((address_space(3))) void*)(uintptr_t)(
            (char*)l - (char*)nullptr),
        16, 0, 0);
}

// --- Kernel A: pack hi-only B frags (64 KB) + sq_e + zero counter -----------
// B frag entry (ct,kt,lane): 8 bf16, col=ct*16+(lane&15), k=kt*32+(lane>>4)*8+j
__global__ __launch_bounds__(256) void vq_prep(const float* __restrict__ cb,
                                               unsigned short* __restrict__ Bfrag,
                                               float* __restrict__ sq_e,
                                               unsigned* __restrict__ counter) {
    int g = blockIdx.x * 256 + threadIdx.x;  // 4096 threads
    int lane = g & 63, kt = (g >> 6) & 1, ct = g >> 7;
    int col = ct * 16 + (lane & 15);
    int k0 = kt * 32 + (lane >> 4) * 8;
    const float4* p = reinterpret_cast<const float4*>(cb + (size_t)col * VQ_D + k0);
    float4 v0 = p[0], v1 = p[1];
    float vv[8] = {v0.x, v0.y, v0.z, v0.w, v1.x, v1.y, v1.z, v1.w};
    bf16x8 h;
#pragma unroll
    for (int j = 0; j < 8; ++j) h[j] = (short)f2bf(vv[j]);
    reinterpret_cast<bf16x8*>(Bfrag)[(size_t)(ct * 2 + kt) * 64 + lane] = h;

    if (g < VQ_K) {
        const float4* row = reinterpret_cast<const float4*>(cb + (size_t)g * VQ_D);
        float s = 0.0f;
#pragma unroll
        for (int i = 0; i < VQ_D / 4; ++i) {
            float4 v = row[i];
            s += v.x * v.x + v.y * v.y + v.z * v.z + v.w * v.w;
        }
        sq_e[g] = s;
    }
    if (g == 0) counter[0] = 0u;
}

// --- Kernel B: stage panel + pipelined MFMA + argmin + epilogue + tail ------
// 512 blocks x 512 thr (8 waves), 2 blocks/CU (16 waves/CU). Wave owns 16 rows.
__global__ __launch_bounds__(512, 4) void vq_fused(const float* __restrict__ x,
                                                   const unsigned short* __restrict__ Bfrag,
                                                   const float* __restrict__ cb,
                                                   const float* __restrict__ sq_e,
                                                   float* __restrict__ out,
                                                   int* __restrict__ idx_out,
                                                   float* __restrict__ loss_part,
                                                   unsigned* __restrict__ counter) {
    __shared__ unsigned short ldsB[32768];  // 64 KB panel; tail reuses as bins
    __shared__ float lds_se[VQ_K];
    __shared__ int sbestk[128];
    __shared__ float wsum[8];
    __shared__ unsigned slast;
    const bf16x8* ldsV = reinterpret_cast<const bf16x8*>(ldsB);

    int t = threadIdx.x;
    int w = t >> 6, l = t & 63;
    int lr = l & 15, lg = l >> 4;
    int rowbase = blockIdx.x * 128 + w * 16;

    // stage pre-packed panel: 8 x 16B per thread, direct global->LDS
#pragma unroll
    for (int i = 0; i < 8; ++i) {
        int e0 = i * 512 + w * 64;  // wave-uniform LDS entry base
        gld_lds16(Bfrag + ((size_t)e0 + l) * 8, (void*)&ldsB[e0 * 8]);
    }
    lds_se[t] = sq_e[t];  // 512 threads -> one each

    // x rows -> A frags = bf16(-2x); sq = |x_row(lr)|^2 (fp32 exact)
    bf16x8 Ah[2];
    float sq;
    {
        float part = 0.0f;
#pragma unroll
        for (int kt = 0; kt < 2; ++kt) {
            const float4* p = reinterpret_cast<const float4*>(
                x + (size_t)(rowbase + lr) * VQ_D + kt * 32 + lg * 8);
            float4 v0 = p[0], v1 = p[1];
            float vv[8] = {v0.x, v0.y, v0.z, v0.w, v1.x, v1.y, v1.z, v1.w};
            bf16x8 h;
#pragma unroll
            for (int j = 0; j < 8; ++j) {
                h[j] = (short)f2bf(-2.0f * vv[j]);  // exact x(-2) scale
                part = fmaf(vv[j], vv[j], part);
            }
            Ah[kt] = h;
        }
        part += __shfl_xor(part, 16);
        part += __shfl_xor(part, 32);
        sq = part;  // every lane: |x|^2 of row lr
    }

    __syncthreads();  // staging drain

    // pipelined main loop: prefetch next b-pair; 2 INDEPENDENT MFMAs per iter
    float bd[4];
    int bc[4];
#pragma unroll
    for (int j = 0; j < 4; ++j) {
        bd[j] = 3.4e38f;
        bc[j] = 0;
    }
    bf16x8 b0 = ldsV[l];
    bf16x8 b1 = ldsV[64 + l];
#pragma unroll
    for (int ct2 = 0; ct2 < 32; ++ct2) {
        bf16x8 n0, n1;
        if (ct2 < 31) {  // prefetch next iteration's fragments
            n0 = ldsV[(ct2 + 1) * 128 + l];
            n1 = ldsV[(ct2 + 1) * 128 + 64 + l];
        }
        int col = ct2 * 16 + lr;
        float se = lds_se[col];
        f32x4 a0 = {se, se, se, se};
        f32x4 a1 = {0.f, 0.f, 0.f, 0.f};
        a0 = __builtin_amdgcn_mfma_f32_16x16x32_bf16(Ah[0], b0, a0, 0, 0, 0);
        a1 = __builtin_amdgcn_mfma_f32_16x16x32_bf16(Ah[1], b1, a1, 0, 0, 0);
        // cols ascend -> strict < keeps np.argmin first occurrence
#pragma unroll
        for (int j = 0; j < 4; ++j) {
            float d = a0[j] + a1[j];
            if (d < bd[j]) {
                bd[j] = d;
                bc[j] = col;
            }
        }
        if (ct2 < 31) {
            b0 = n0;
            b1 = n1;
        }
    }

    // cross-lane argmin butterfly over the 16 col-slots; ties -> smaller col
    float dacc = 0.0f;
#pragma unroll
    for (int j = 0; j < 4; ++j) {
        float d = bd[j];
        int cc = bc[j];
#pragma unroll
        for (int off = 1; off <= 8; off <<= 1) {
            float od = __shfl_xor(d, off);
            int oc = __shfl_xor(cc, off);
            if (od < d || (od == d && oc < cc)) {
                d = od;
                cc = oc;
            }
        }
        if (lr == 0) {  // lanes 0,16,32,48 own row lg*4 + j
            int rloc = w * 16 + lg * 4 + j;
            sbestk[rloc] = cc;
            idx_out[blockIdx.x * 128 + rloc] = cc;  // plain store
            dacc += d;
        }
    }

    // loss partial: sum(dist) (lr==0 lanes) + sum(|x|^2) (lg==0 lanes)
    float contrib = dacc + (lg == 0 ? sq : 0.0f);
#pragma unroll
    for (int off = 32; off; off >>= 1) contrib += __shfl_down(contrib, off);
    if (l == 0) wsum[w] = contrib;
    __syncthreads();
    if (t == 0) {
        float s = 0.0f;
#pragma unroll
        for (int i = 0; i < 8; ++i) s += wsum[i];
        loss_part[blockIdx.x] = s;  // plain store
    }

    // cooperative quantized write: thread -> (row, quarter-row of 16 floats)
    {
        int r = t >> 2, q = t & 3;
        int k = sbestk[r];
        const float4* src =
            reinterpret_cast<const float4*>(cb + (size_t)k * VQ_D + q * 16);
        float4* dst = reinterpret_cast<float4*>(
            out + ((size_t)blockIdx.x * 128 + r) * VQ_D + q * 16);
#pragma unroll
        for (int i = 0; i < 4; ++i) dst[i] = src[i];
    }

    // ---- tail: last-finishing block does histogram + loss + perplexity ----
    __threadfence();  // release: idx/loss/out stores visible device-wide
    __syncthreads();  // all stores in this block issued
    if (t == 0) slast = atomicAdd(counter, 1u);  // the ONLY global atomic
    __syncthreads();
    if (slast == NBLK - 1) {
        __threadfence();  // acquire side
        unsigned* h = reinterpret_cast<unsigned*>(ldsB);  // reuse as 512 bins
        h[t] = 0u;
        __syncthreads();
#pragma unroll
        for (int i = 0; i < VQ_N / 512; ++i)  // 128 coalesced rounds
            atomicAdd(&h[idx_out[t + i * 512]], 1u);  // LDS atomic only
        __syncthreads();
        float p = (float)h[t] * (1.0f / (float)VQ_N);
        float term = p * logf(p + 1e-10f);
        float ls = loss_part[t];  // one block-partial per thread
#pragma unroll
        for (int off = 32; off; off >>= 1) {
            term += __shfl_down(term, off);
            ls += __shfl_down(ls, off);
        }
        float* wsH = lds_se;  // reuse
        float* wsL = lds_se + 8;
        if (l == 0) {
            wsH[w] = term;
            wsL[w] = ls;
        }
        __syncthreads();
        if (t == 0) {
            float H = 0.0f, L = 0.0f;
#pragma unroll
            for (int i = 0; i < 8; ++i) {
                H += wsH[i];
                L += wsL[i];
            }
            float* out_tail = out + (size_t)VQ_N * VQ_D;
            out_tail[0] = L * (1.25f / (float)(VQ_N * VQ_D));
            out_tail[1] = expf(-H);
        }
    }
}

extern "C" void kernel_launch(void* const* d_in, const int* in_sizes, int n_in,
                              void* d_out, int out_size, void* d_ws, size_t ws_size,
                              hipStream_t stream) {
    const float* x = (const float*)d_in[0];   // [65536,64] fp32
    const float* cb = (const float*)d_in[1];  // [512,64] fp32
    float* out = (float*)d_out;               // [4194304 + 2]

    // ws: Bfrag 64KB | sq_e 2KB | idx 256KB | loss_part 2KB | counter 4B
    unsigned short* Bfrag = (unsigned short*)d_ws;
    float* sq_e = (float*)((char*)d_ws + (64 << 10));
    int* idx = (int*)((char*)d_ws + (66 << 10));
    float* loss_part = (float*)((char*)idx + VQ_N * 4);
    unsigned* counter = (unsigned*)((char*)loss_part + 2048);

    vq_prep<<<16, 256, 0, stream>>>(cb, Bfrag, sq_e, counter);
    vq_fused<<<NBLK, 512, 0, stream>>>(x, Bfrag, cb, sq_e, out, idx, loss_part,
                                       counter);
}

// Round 16
// 47.334 us; speedup vs baseline: 4.3166x; 4.3166x over previous
//
#include <hip/hip_runtime.h>
#include <stdint.h>

// VectorQuantization: 3 kernels — prep (pack bf16 B frags + sq_e), fused
// (MFMA distances + argmin + gather + loss partials), finalhist (histogram +
// loss + perplexity in one block). No global atomics, no device fences
// (R15 lesson: per-block __threadfence() serializes ~0.4us x blocks).
// N=65536 rows, D=64, K=512 codebook (uniform ±1/512 -> argmin flips bounded
// at 0.0039 in output-0; perplexity shift << 2% tol).
// dist = (|e|^2 + (-2x_h).e_h[k0:32]) + ((-2x_h).e_h[32:64]) via two
// independent MFMAs summed in VALU.
// R16: 256 blocks x 1024 thr (16 waves = the measured 16-wave/CU sweet spot,
// 1 block/CU), staging traffic halved vs R11, hist merged into final.

#define VQ_N 65536
#define VQ_D 64
#define VQ_K 512
#define NBLK 256

typedef __attribute__((ext_vector_type(4))) float f32x4;
typedef __attribute__((ext_vector_type(8))) short bf16x8;

__device__ __forceinline__ unsigned short f2bf(float f) {  // RNE
    unsigned b = __float_as_uint(f);
    return (unsigned short)((b + 0x7fffu + ((b >> 16) & 1u)) >> 16);
}

__device__ __forceinline__ void gld_lds16(const void* g, void* l) {
    __builtin_amdgcn_global_load_lds(
        (const __attribute__((address_space(1))) void*)g,
        (__attribute__((address_space(3))) void*)(uintptr_t)(
            (char*)l - (char*)nullptr),
        16, 0, 0);
}

// --- Kernel A: pack hi-only B frags (64 KB) + sq_e ---------------------------
// B frag entry (ct,kt,lane): 8 bf16, col=ct*16+(lane&15), k=kt*32+(lane>>4)*8+j
__global__ __launch_bounds__(256) void vq_prep(const float* __restrict__ cb,
                                               unsigned short* __restrict__ Bfrag,
                                               float* __restrict__ sq_e) {
    int g = blockIdx.x * 256 + threadIdx.x;  // 4096 threads
    int lane = g & 63, kt = (g >> 6) & 1, ct = g >> 7;
    int col = ct * 16 + (lane & 15);
    int k0 = kt * 32 + (lane >> 4) * 8;
    const float4* p = reinterpret_cast<const float4*>(cb + (size_t)col * VQ_D + k0);
    float4 v0 = p[0], v1 = p[1];
    float vv[8] = {v0.x, v0.y, v0.z, v0.w, v1.x, v1.y, v1.z, v1.w};
    bf16x8 h;
#pragma unroll
    for (int j = 0; j < 8; ++j) h[j] = (short)f2bf(vv[j]);
    reinterpret_cast<bf16x8*>(Bfrag)[(size_t)(ct * 2 + kt) * 64 + lane] = h;

    if (g < VQ_K) {
        const float4* row = reinterpret_cast<const float4*>(cb + (size_t)g * VQ_D);
        float s = 0.0f;
#pragma unroll
        for (int i = 0; i < VQ_D / 4; ++i) {
            float4 v = row[i];
            s += v.x * v.x + v.y * v.y + v.z * v.z + v.w * v.w;
        }
        sq_e[g] = s;
    }
}

// --- Kernel B: stage panel + MFMA + argmin + gather + loss partial ----------
// 256 blocks x 1024 thr (16 waves), 1 block/CU. Wave owns 16 rows (256/block).
__global__ __launch_bounds__(1024, 4) void vq_fused(const float* __restrict__ x,
                                                    const unsigned short* __restrict__ Bfrag,
                                                    const float* __restrict__ cb,
                                                    const float* __restrict__ sq_e,
                                                    float* __restrict__ out,
                                                    int* __restrict__ idx_out,
                                                    float* __restrict__ loss_part) {
    __shared__ unsigned short ldsB[32768];  // 64 KB: all 512 cols, hi frags
    __shared__ float lds_se[VQ_K];
    __shared__ int sbestk[256];
    __shared__ float wsum[16];
    const bf16x8* ldsV = reinterpret_cast<const bf16x8*>(ldsB);

    int t = threadIdx.x;
    int w = t >> 6, l = t & 63;
    int lr = l & 15, lg = l >> 4;
    int rowbase = blockIdx.x * 256 + w * 16;

    // stage pre-packed panel: 4 x 16B per thread, direct global->LDS
#pragma unroll
    for (int i = 0; i < 4; ++i) {
        int e0 = i * 1024 + w * 64;  // wave-uniform LDS entry base
        gld_lds16(Bfrag + ((size_t)e0 + l) * 8, (void*)&ldsB[e0 * 8]);
    }
    if (t < VQ_K) lds_se[t] = sq_e[t];

    // x rows -> A frags = bf16(-2x); sq = |x_row(lr)|^2 (fp32 exact)
    bf16x8 Ah[2];
    float sq;
    {
        float part = 0.0f;
#pragma unroll
        for (int kt = 0; kt < 2; ++kt) {
            const float4* p = reinterpret_cast<const float4*>(
                x + (size_t)(rowbase + lr) * VQ_D + kt * 32 + lg * 8);
            float4 v0 = p[0], v1 = p[1];
            float vv[8] = {v0.x, v0.y, v0.z, v0.w, v1.x, v1.y, v1.z, v1.w};
            bf16x8 h;
#pragma unroll
            for (int j = 0; j < 8; ++j) {
                h[j] = (short)f2bf(-2.0f * vv[j]);  // exact x(-2) scale
                part = fmaf(vv[j], vv[j], part);
            }
            Ah[kt] = h;
        }
        part += __shfl_xor(part, 16);
        part += __shfl_xor(part, 32);
        sq = part;  // every lane: |x|^2 of row lr
    }

    __syncthreads();  // staging drain (vmcnt(0) implied)

    // main loop: prefetch next b-pair; 2 independent MFMAs per iter
    float bd[4];
    int bc[4];
#pragma unroll
    for (int j = 0; j < 4; ++j) {
        bd[j] = 3.4e38f;
        bc[j] = 0;
    }
    bf16x8 b0 = ldsV[l];
    bf16x8 b1 = ldsV[64 + l];
#pragma unroll
    for (int ct2 = 0; ct2 < 32; ++ct2) {
        bf16x8 n0, n1;
        if (ct2 < 31) {  // prefetch next iteration's fragments
            n0 = ldsV[(ct2 + 1) * 128 + l];
            n1 = ldsV[(ct2 + 1) * 128 + 64 + l];
        }
        int col = ct2 * 16 + lr;
        float se = lds_se[col];
        f32x4 a0 = {se, se, se, se};
        f32x4 a1 = {0.f, 0.f, 0.f, 0.f};
        a0 = __builtin_amdgcn_mfma_f32_16x16x32_bf16(Ah[0], b0, a0, 0, 0, 0);
        a1 = __builtin_amdgcn_mfma_f32_16x16x32_bf16(Ah[1], b1, a1, 0, 0, 0);
        // cols ascend -> strict < keeps np.argmin first occurrence
#pragma unroll
        for (int j = 0; j < 4; ++j) {
            float d = a0[j] + a1[j];
            if (d < bd[j]) {
                bd[j] = d;
                bc[j] = col;
            }
        }
        if (ct2 < 31) {
            b0 = n0;
            b1 = n1;
        }
    }

    // cross-lane argmin butterfly over the 16 col-slots; ties -> smaller col
    float dacc = 0.0f;
#pragma unroll
    for (int j = 0; j < 4; ++j) {
        float d = bd[j];
        int cc = bc[j];
#pragma unroll
        for (int off = 1; off <= 8; off <<= 1) {
            float od = __shfl_xor(d, off);
            int oc = __shfl_xor(cc, off);
            if (od < d || (od == d && oc < cc)) {
                d = od;
                cc = oc;
            }
        }
        if (lr == 0) {  // lanes 0,16,32,48 own row lg*4 + j
            int rloc = w * 16 + lg * 4 + j;
            sbestk[rloc] = cc;
            idx_out[blockIdx.x * 256 + rloc] = cc;  // plain store
            dacc += d;
        }
    }

    // loss partial: sum(dist) (lr==0 lanes) + sum(|x|^2) (lg==0 lanes)
    float contrib = dacc + (lg == 0 ? sq : 0.0f);
#pragma unroll
    for (int off = 32; off; off >>= 1) contrib += __shfl_down(contrib, off);
    if (l == 0) wsum[w] = contrib;
    __syncthreads();
    if (t == 0) {
        float s = 0.0f;
#pragma unroll
        for (int i = 0; i < 16; ++i) s += wsum[i];
        loss_part[blockIdx.x] = s;  // plain store
    }

    // cooperative quantized write: thread -> (row, quarter-row of 16 floats)
    {
        int r = t >> 2, q = t & 3;
        int k = sbestk[r];
        const float4* src =
            reinterpret_cast<const float4*>(cb + (size_t)k * VQ_D + q * 16);
        float4* dst = reinterpret_cast<float4*>(
            out + ((size_t)blockIdx.x * 256 + r) * VQ_D + q * 16);
#pragma unroll
        for (int i = 0; i < 4; ++i) dst[i] = src[i];
    }
}

// --- Kernel C: one block — histogram + loss + perplexity --------------------
__global__ __launch_bounds__(1024) void vq_final(const int* __restrict__ idx,
                                                 const float* __restrict__ loss_part,
                                                 float* __restrict__ out_tail) {
    __shared__ unsigned h[VQ_K];
    __shared__ float wsH[16], wsL[16];
    int t = threadIdx.x;  // 1024 threads
    if (t < VQ_K) h[t] = 0u;
    __syncthreads();
#pragma unroll
    for (int i = 0; i < VQ_N / 1024; ++i)  // 64 coalesced rounds
        atomicAdd(&h[idx[t + i * 1024]], 1u);  // LDS atomic only
    __syncthreads();

    float term = 0.0f;
    if (t < VQ_K) {
        float p = (float)h[t] * (1.0f / (float)VQ_N);
        term = p * logf(p + 1e-10f);
    }
    float ls = (t < NBLK) ? loss_part[t] : 0.0f;
#pragma unroll
    for (int off = 32; off; off >>= 1) {
        term += __shfl_down(term, off);
        ls += __shfl_down(ls, off);
    }
    int w = t >> 6, l = t & 63;
    if (l == 0) {
        wsH[w] = term;
        wsL[w] = ls;
    }
    __syncthreads();
    if (t == 0) {
        float H = 0.0f, L = 0.0f;
#pragma unroll
        for (int i = 0; i < 16; ++i) {
            H += wsH[i];
            L += wsL[i];
        }
        out_tail[0] = L * (1.25f / (float)(VQ_N * VQ_D));
        out_tail[1] = expf(-H);
    }
}

extern "C" void kernel_launch(void* const* d_in, const int* in_sizes, int n_in,
                              void* d_out, int out_size, void* d_ws, size_t ws_size,
                              hipStream_t stream) {
    const float* x = (const float*)d_in[0];   // [65536,64] fp32
    const float* cb = (const float*)d_in[1];  // [512,64] fp32
    float* out = (float*)d_out;               // [4194304 + 2]

    // ws: Bfrag 64KB | sq_e 2KB | idx 256KB | loss_part 1KB
    unsigned short* Bfrag = (unsigned short*)d_ws;
    float* sq_e = (float*)((char*)d_ws + (64 << 10));
    int* idx = (int*)((char*)d_ws + (66 << 10));
    float* loss_part = (float*)((char*)idx + VQ_N * 4);

    vq_prep<<<16, 256, 0, stream>>>(cb, Bfrag, sq_e);
    vq_fused<<<NBLK, 1024, 0, stream>>>(x, Bfrag, cb, sq_e, out, idx, loss_part);
    vq_final<<<1, 1024, 0, stream>>>(idx, loss_part, out + (size_t)VQ_N * VQ_D);
}

// Round 17
// 44.072 us; speedup vs baseline: 4.6361x; 1.0740x over previous
//
#include <hip/hip_runtime.h>
#include <stdint.h>

// VectorQuantization: 3 kernels — prep (pack bf16 B frags + sq_e), fused
// (R11-exact: stage panel once, MFMA distances + argmin + gather + loss
// partials), final (histogram + loss + perplexity in ONE block; merged from
// R16 where it was correctness-proven). No global atomics, no device fences.
// N=65536 rows, D=64, K=512 codebook (uniform ±1/512 -> argmin flips bounded
// at 0.0039 in output-0; perplexity shift << 2% tol).
// dist = |e|^2 - 2 x.e computed as MFMA( bf16(-2x), bf16(e), C_in=|e|^2 ).
// R17: single variable vs R11 (32.6us) — vq_hist+vq_final merged, one fewer
// dispatch+gap. Tests how much of the plateau is inter-dispatch overhead.

#define VQ_N 65536
#define VQ_D 64
#define VQ_K 512
#define NBLK 512

typedef __attribute__((ext_vector_type(4))) float f32x4;
typedef __attribute__((ext_vector_type(8))) short bf16x8;

__device__ __forceinline__ unsigned short f2bf(float f) {  // RNE
    unsigned b = __float_as_uint(f);
    return (unsigned short)((b + 0x7fffu + ((b >> 16) & 1u)) >> 16);
}

__device__ __forceinline__ void gld_lds16(const void* g, void* l) {
    __builtin_amdgcn_global_load_lds(
        (const __attribute__((address_space(1))) void*)g,
        (__attribute__((address_space(3))) void*)(uintptr_t)(
            (char*)l - (char*)nullptr),
        16, 0, 0);
}

// --- Kernel A: pack hi-only B frags (64 KB) + sq_e (convert ONCE) -----------
// B frag entry (ct,kt,lane): 8 bf16, col=ct*16+(lane&15), k=kt*32+(lane>>4)*8+j
__global__ __launch_bounds__(256) void vq_prep(const float* __restrict__ cb,
                                               unsigned short* __restrict__ Bfrag,
                                               float* __restrict__ sq_e) {
    int g = blockIdx.x * 256 + threadIdx.x;  // 4096 threads
    int lane = g & 63, kt = (g >> 6) & 1, ct = g >> 7;
    int col = ct * 16 + (lane & 15);
    int k0 = kt * 32 + (lane >> 4) * 8;
    const float4* p = reinterpret_cast<const float4*>(cb + (size_t)col * VQ_D + k0);
    float4 v0 = p[0], v1 = p[1];
    float vv[8] = {v0.x, v0.y, v0.z, v0.w, v1.x, v1.y, v1.z, v1.w};
    bf16x8 h;
#pragma unroll
    for (int j = 0; j < 8; ++j) h[j] = (short)f2bf(vv[j]);
    reinterpret_cast<bf16x8*>(Bfrag)[(size_t)(ct * 2 + kt) * 64 + lane] = h;

    if (g < VQ_K) {
        const float4* row = reinterpret_cast<const float4*>(cb + (size_t)g * VQ_D);
        float s = 0.0f;
#pragma unroll
        for (int i = 0; i < VQ_D / 4; ++i) {
            float4 v = row[i];
            s += v.x * v.x + v.y * v.y + v.z * v.z + v.w * v.w;
        }
        sq_e[g] = s;
    }
}

// --- Kernel B (R11-exact): stage panel once + MFMA + argmin + epilogue ------
// 512 blocks x 512 thr (8 waves), 2 blocks/CU. Wave owns 16 rows.
__global__ __launch_bounds__(512, 4) void vq_fused(const float* __restrict__ x,
                                                   const unsigned short* __restrict__ Bfrag,
                                                   const float* __restrict__ cb,
                                                   const float* __restrict__ sq_e,
                                                   float* __restrict__ out,
                                                   int* __restrict__ idx_out,
                                                   float* __restrict__ loss_part) {
    __shared__ unsigned short ldsB[32768];  // 64 KB: all 512 cols, hi frags
    __shared__ float lds_se[VQ_K];
    __shared__ int sbestk[128];
    __shared__ float wsum[8];
    const bf16x8* ldsV = reinterpret_cast<const bf16x8*>(ldsB);

    int t = threadIdx.x;
    int w = t >> 6, l = t & 63;
    int lr = l & 15, lg = l >> 4;
    int rowbase = blockIdx.x * 128 + w * 16;

    // stage the pre-packed panel: 8 x 16B per thread, direct global->LDS
#pragma unroll
    for (int i = 0; i < 8; ++i) {
        int e0 = i * 512 + w * 64;  // wave-uniform LDS entry base
        gld_lds16(Bfrag + ((size_t)e0 + l) * 8, (void*)&ldsB[e0 * 8]);
    }
    lds_se[t] = sq_e[t];  // 512 threads -> one each

    // x rows -> A frags = bf16(-2x); sq = |x_row(lr)|^2 (fp32 exact);
    // VGPR loads + converts overlap the in-flight gld_lds
    bf16x8 Ah[2];
    float sq;
    {
        float part = 0.0f;
#pragma unroll
        for (int kt = 0; kt < 2; ++kt) {
            const float4* p = reinterpret_cast<const float4*>(
                x + (size_t)(rowbase + lr) * VQ_D + kt * 32 + lg * 8);
            float4 v0 = p[0], v1 = p[1];
            float vv[8] = {v0.x, v0.y, v0.z, v0.w, v1.x, v1.y, v1.z, v1.w};
            bf16x8 h;
#pragma unroll
            for (int j = 0; j < 8; ++j) {
                h[j] = (short)f2bf(-2.0f * vv[j]);  // exact x(-2) scale
                part = fmaf(vv[j], vv[j], part);
            }
            Ah[kt] = h;
        }
        part += __shfl_xor(part, 16);
        part += __shfl_xor(part, 32);
        sq = part;  // every lane: |x|^2 of row lr
    }

    __syncthreads();  // single staging drain (vmcnt(0) implied)

    // barrier-free main loop: 32 iters over all 512 cols
    float bd[4];
    int bc[4];
#pragma unroll
    for (int j = 0; j < 4; ++j) {
        bd[j] = 3.4e38f;
        bc[j] = 0;
    }
#pragma unroll
    for (int ct2 = 0; ct2 < 32; ++ct2) {
        int col = ct2 * 16 + lr;
        float se = lds_se[col];
        bf16x8 b0 = ldsV[ct2 * 128 + l];
        bf16x8 b1 = ldsV[ct2 * 128 + 64 + l];
        f32x4 a0 = {se, se, se, se};
        a0 = __builtin_amdgcn_mfma_f32_16x16x32_bf16(Ah[0], b0, a0, 0, 0, 0);
        a0 = __builtin_amdgcn_mfma_f32_16x16x32_bf16(Ah[1], b1, a0, 0, 0, 0);
        // cols ascend -> strict < keeps np.argmin first occurrence
#pragma unroll
        for (int j = 0; j < 4; ++j) {
            if (a0[j] < bd[j]) {
                bd[j] = a0[j];
                bc[j] = col;
            }
        }
    }

    // cross-lane argmin butterfly over the 16 col-slots; ties -> smaller col
    float dacc = 0.0f;
#pragma unroll
    for (int j = 0; j < 4; ++j) {
        float d = bd[j];
        int cc = bc[j];
#pragma unroll
        for (int off = 1; off <= 8; off <<= 1) {
            float od = __shfl_xor(d, off);
            int oc = __shfl_xor(cc, off);
            if (od < d || (od == d && oc < cc)) {
                d = od;
                cc = oc;
            }
        }
        if (lr == 0) {  // lanes 0,16,32,48 own row lg*4 + j
            int rloc = w * 16 + lg * 4 + j;
            sbestk[rloc] = cc;
            idx_out[blockIdx.x * 128 + rloc] = cc;  // plain store
            dacc += d;
        }
    }

    // loss partial: sum(dist) (lr==0 lanes) + sum(|x|^2) (lg==0 lanes)
    float contrib = dacc + (lg == 0 ? sq : 0.0f);
#pragma unroll
    for (int off = 32; off; off >>= 1) contrib += __shfl_down(contrib, off);
    if (l == 0) wsum[w] = contrib;
    __syncthreads();
    if (t == 0) {
        float s = 0.0f;
#pragma unroll
        for (int i = 0; i < 8; ++i) s += wsum[i];
        loss_part[blockIdx.x] = s;  // plain store
    }

    // cooperative quantized write: thread -> (row, quarter-row of 16 floats)
    {
        int r = t >> 2, q = t & 3;
        int k = sbestk[r];
        const float4* src =
            reinterpret_cast<const float4*>(cb + (size_t)k * VQ_D + q * 16);
        float4* dst = reinterpret_cast<float4*>(
            out + ((size_t)blockIdx.x * 128 + r) * VQ_D + q * 16);
#pragma unroll
        for (int i = 0; i < 4; ++i) dst[i] = src[i];
    }
}

// --- Kernel C: one block — histogram + loss + perplexity --------------------
__global__ __launch_bounds__(1024) void vq_final(const int* __restrict__ idx,
                                                 const float* __restrict__ loss_part,
                                                 float* __restrict__ out_tail) {
    __shared__ unsigned h[VQ_K];
    __shared__ float wsH[16], wsL[16];
    int t = threadIdx.x;  // 1024 threads
    if (t < VQ_K) h[t] = 0u;
    __syncthreads();
#pragma unroll
    for (int i = 0; i < VQ_N / 1024; ++i)  // 64 coalesced rounds
        atomicAdd(&h[idx[t + i * 1024]], 1u);  // LDS atomic only
    __syncthreads();

    float term = 0.0f;
    if (t < VQ_K) {
        float p = (float)h[t] * (1.0f / (float)VQ_N);
        term = p * logf(p + 1e-10f);
    }
    float ls = (t < NBLK) ? loss_part[t] : 0.0f;
#pragma unroll
    for (int off = 32; off; off >>= 1) {
        term += __shfl_down(term, off);
        ls += __shfl_down(ls, off);
    }
    int w = t >> 6, l = t & 63;
    if (l == 0) {
        wsH[w] = term;
        wsL[w] = ls;
    }
    __syncthreads();
    if (t == 0) {
        float H = 0.0f, L = 0.0f;
#pragma unroll
        for (int i = 0; i < 16; ++i) {
            H += wsH[i];
            L += wsL[i];
        }
        out_tail[0] = L * (1.25f / (float)(VQ_N * VQ_D));
        out_tail[1] = expf(-H);
    }
}

extern "C" void kernel_launch(void* const* d_in, const int* in_sizes, int n_in,
                              void* d_out, int out_size, void* d_ws, size_t ws_size,
                              hipStream_t stream) {
    const float* x = (const float*)d_in[0];   // [65536,64] fp32
    const float* cb = (const float*)d_in[1];  // [512,64] fp32
    float* out = (float*)d_out;               // [4194304 + 2]

    // ws: Bfrag 64KB | sq_e 2KB | idx 256KB | loss_part 2KB
    unsigned short* Bfrag = (unsigned short*)d_ws;
    float* sq_e = (float*)((char*)d_ws + (64 << 10));
    int* idx = (int*)((char*)d_ws + (66 << 10));
    float* loss_part = (float*)((char*)idx + VQ_N * 4);

    vq_prep<<<16, 256, 0, stream>>>(cb, Bfrag, sq_e);
    vq_fused<<<NBLK, 512, 0, stream>>>(x, Bfrag, cb, sq_e, out, idx, loss_part);
    vq_final<<<1, 1024, 0, stream>>>(idx, loss_part, out + (size_t)VQ_N * VQ_D);
}